// Round 1
// 504.293 us; speedup vs baseline: 1.0205x; 1.0205x over previous
//
#include <hip/hip_runtime.h>
#include <stdint.h>

#define VOCAB  50257
#define HIDDEN 2048
#define NTOK   (8 * 2048)   // BATCH * SEQ
#define TOPK   256
#define WPB    4            // independent waves (rows) per block

// One WAVE per row, zero barriers, zero atomics.
// v2 changes vs v1 (514 us harness):
//  - bisection bounds derived from data: lo = wave_min(per-lane 4th largest)
//    (count_ge(lo) >= 4*64 = 256 by construction), hi = wave_max  -> ~7 rounds
//    instead of ~18 over the full u32 range.
//  - count_ge: per-lane VGPR counts + 12-op DPP wave reduce + readlane,
//    replacing 32x (ballot -> s_bcnt1 -> s_add) scalar-pipe chains per round.
//  - scatter: one DPP prefix scan + lane-local compaction (static reg indexing),
//    replacing 32 ballot-prefix steps.
// Tie-fallback path and bitonic sort are unchanged (verified in prior session).

// ---- wave64 DPP scan/reduce (rocPRIM-canonical row_shr/row_bcast sequence) ----
__device__ __forceinline__ uint32_t umax32(uint32_t a, uint32_t b) { return a > b ? a : b; }
__device__ __forceinline__ uint32_t umin32(uint32_t a, uint32_t b) { return a < b ? a : b; }

__device__ __forceinline__ uint32_t scan_add(uint32_t v) {
    // inclusive prefix sum across 64 lanes; lane 63 holds the total
    v += (uint32_t)__builtin_amdgcn_update_dpp(0, (int)v, 0x111, 0xf, 0xf, false); // row_shr:1
    v += (uint32_t)__builtin_amdgcn_update_dpp(0, (int)v, 0x112, 0xf, 0xf, false); // row_shr:2
    v += (uint32_t)__builtin_amdgcn_update_dpp(0, (int)v, 0x114, 0xf, 0xf, false); // row_shr:4
    v += (uint32_t)__builtin_amdgcn_update_dpp(0, (int)v, 0x118, 0xf, 0xf, false); // row_shr:8
    v += (uint32_t)__builtin_amdgcn_update_dpp(0, (int)v, 0x142, 0xa, 0xf, false); // row_bcast:15 -> rows 1,3
    v += (uint32_t)__builtin_amdgcn_update_dpp(0, (int)v, 0x143, 0xc, 0xf, false); // row_bcast:31 -> rows 2,3
    return v;
}
__device__ __forceinline__ uint32_t wave_sum(uint32_t v) {
    return (uint32_t)__builtin_amdgcn_readlane((int)scan_add(v), 63);
}
__device__ __forceinline__ uint32_t wave_max(uint32_t v) {
    v = umax32(v, (uint32_t)__builtin_amdgcn_update_dpp(0, (int)v, 0x111, 0xf, 0xf, false));
    v = umax32(v, (uint32_t)__builtin_amdgcn_update_dpp(0, (int)v, 0x112, 0xf, 0xf, false));
    v = umax32(v, (uint32_t)__builtin_amdgcn_update_dpp(0, (int)v, 0x114, 0xf, 0xf, false));
    v = umax32(v, (uint32_t)__builtin_amdgcn_update_dpp(0, (int)v, 0x118, 0xf, 0xf, false));
    v = umax32(v, (uint32_t)__builtin_amdgcn_update_dpp(0, (int)v, 0x142, 0xa, 0xf, false));
    v = umax32(v, (uint32_t)__builtin_amdgcn_update_dpp(0, (int)v, 0x143, 0xc, 0xf, false));
    return (uint32_t)__builtin_amdgcn_readlane((int)v, 63);
}
__device__ __forceinline__ uint32_t wave_min(uint32_t v) {
    // old = -1: masked/invalid lanes contribute 0xFFFFFFFF (neutral for min)
    v = umin32(v, (uint32_t)__builtin_amdgcn_update_dpp(-1, (int)v, 0x111, 0xf, 0xf, false));
    v = umin32(v, (uint32_t)__builtin_amdgcn_update_dpp(-1, (int)v, 0x112, 0xf, 0xf, false));
    v = umin32(v, (uint32_t)__builtin_amdgcn_update_dpp(-1, (int)v, 0x114, 0xf, 0xf, false));
    v = umin32(v, (uint32_t)__builtin_amdgcn_update_dpp(-1, (int)v, 0x118, 0xf, 0xf, false));
    v = umin32(v, (uint32_t)__builtin_amdgcn_update_dpp(-1, (int)v, 0x142, 0xa, 0xf, false));
    v = umin32(v, (uint32_t)__builtin_amdgcn_update_dpp(-1, (int)v, 0x143, 0xc, 0xf, false));
    return (uint32_t)__builtin_amdgcn_readlane((int)v, 63);
}

__device__ __forceinline__ void cmpex(uint64_t& a, uint64_t& b, bool desc) {
    bool gt = a > b;               // keys are distinct, no equal case
    uint64_t mx = gt ? a : b;
    uint64_t mn = gt ? b : a;
    a = desc ? mx : mn;
    b = desc ? mn : mx;
}

__device__ __forceinline__ void step_xor(uint64_t& v, int r, int lane, int lx, int k) {
    uint64_t p = __shfl_xor(v, lx, 64);
    int i = lane * 4 + r;
    bool desc = ((i & k) == 0);
    bool low  = ((lane & lx) == 0);
    bool keep_max = (desc == low);
    bool gt = v > p;
    v = (keep_max == gt) ? v : p;
}

__global__ __launch_bounds__(256) void topk_kernel(
    const int* __restrict__ ids,
    const float* __restrict__ W,
    float* __restrict__ out)
{
    const int lane = threadIdx.x & 63;
    const int w    = threadIdx.x >> 6;
    const int row  = blockIdx.x * WPB + w;

    __shared__ __align__(16) uint64_t sel[WPB][256];

    const int id = ids[row];
    const float4* src = (const float4*)(W + (size_t)id * HIDDEN);

    // ---- load row, map to order-preserving sortable u32; fuse per-lane top-4 ----
    // element e = c*4 + j lives at row index idx = c*256 + lane*4 + j
    uint32_t sv[32];
    uint32_t m0 = 0u, m1 = 0u, m2 = 0u, m3 = 0u;   // per-lane top-4, descending
#pragma unroll
    for (int c = 0; c < 8; ++c) {
        float4 v = src[c * 64 + lane];
        uint32_t u[4] = {__float_as_uint(v.x), __float_as_uint(v.y),
                         __float_as_uint(v.z), __float_as_uint(v.w)};
#pragma unroll
        for (int j = 0; j < 4; ++j) {
            uint32_t m = (u[j] & 0x80000000u) ? 0xFFFFFFFFu : 0x80000000u;
            uint32_t s = u[j] ^ m;
            sv[c * 4 + j] = s;
            // bubble-insert into per-lane top-4 (7 max/min ops)
            uint32_t b0 = umin32(m0, s);  m0 = umax32(m0, s);
            uint32_t b1 = umin32(m1, b0); m1 = umax32(m1, b0);
            uint32_t b2 = umin32(m2, b1); m2 = umax32(m2, b1);
            m3 = umax32(m3, b2);
        }
    }

    // ---- data-derived bisection bounds ----
    // lo = min over lanes of per-lane 4th-largest: every lane has >=4 elements
    //      >= its own m3 >= lo, so count_ge(lo) >= 4*64 = 256  (invariant holds)
    // hi = global max: count_ge(hi+1) == 0 < 256               (invariant holds)
    uint32_t lo = wave_min(m3);
    uint32_t hi = wave_max(m0);

    // ---- count_ge(T): per-lane VGPR counts, one DPP reduce (scalar-pipe free) ----
    auto count_ge = [&](uint32_t T) -> uint32_t {
        uint32_t c = 0u;
#pragma unroll
        for (int e = 0; e < 32; ++e)
            c += (sv[e] >= T) ? 1u : 0u;
        return wave_sum(c);     // wave-uniform
    };

    // ---- bisection for the top-k value threshold ----
    // invariant: count_ge(lo) >= TOPK, count_ge(hi+1) < TOPK
    uint32_t Tsel = 0u;
    bool exact = false;
    while (lo < hi) {
        uint32_t mid = lo + ((hi - lo) >> 1) + 1u;
        uint32_t c = count_ge(mid);
        if (c == TOPK) { Tsel = mid; exact = true; break; }
        if (c > TOPK) lo = mid; else hi = mid - 1u;
    }

    // ---- build per-lane selection bitmask over the 32 elements ----
    uint32_t selmask = 0u;
    if (exact) {
#pragma unroll
        for (int e = 0; e < 32; ++e)
            if (sv[e] >= Tsel) selmask |= (1u << e);
    } else {
        // value ties at the boundary: take all > vstar, plus the lowest-index equals
        uint32_t vstar = lo;
        uint32_t m = (vstar == 0xFFFFFFFFu) ? 0u : count_ge(vstar + 1u);
        uint32_t r = TOPK - m;                 // equals still needed, by index order
        const uint64_t below = (1ull << lane) - 1ull;
        uint32_t base = 0u;                    // equals in chunks already processed
        for (int c = 0; c < 8; ++c) {
            uint64_t bj[4];
            uint32_t pre = 0u;
#pragma unroll
            for (int j = 0; j < 4; ++j) {
                bj[j] = __ballot(sv[c * 4 + j] == vstar);
                pre += (uint32_t)__popcll(bj[j] & below);
            }
            uint32_t ownpref = 0u;
#pragma unroll
            for (int j = 0; j < 4; ++j) {
                int e = c * 4 + j;
                bool eq = (sv[e] == vstar);
                uint32_t rank = base + pre + ownpref;   // idx order: lane-major, j-minor
                if (sv[e] > vstar || (eq && rank < r)) selmask |= (1u << e);
                ownpref += eq ? 1u : 0u;
            }
#pragma unroll
            for (int j = 0; j < 4; ++j)
                base += (uint32_t)__popcll(bj[j]);
        }
    }

    // ---- scatter the exactly-256 selected keys into LDS ----
    // one DPP prefix scan gives each lane its base; lane-local compaction after
    // that (static register indexing only -> no scratch)
    uint32_t nsel = (uint32_t)__popc(selmask);
    uint32_t pos  = scan_add(nsel) - nsel;     // exclusive prefix over lanes
    const int lane4 = lane * 4;
#pragma unroll
    for (int e = 0; e < 32; ++e) {
        if ((selmask >> e) & 1u) {
            uint32_t idx = (uint32_t)((e >> 2) * 256 + lane4 + (e & 3));
            sel[w][pos] = ((uint64_t)sv[e] << 16) | (uint64_t)(0xFFFFu ^ idx);
            pos++;
        }
    }
    __threadfence_block();

    // ---- bitonic sort 256 keys descending, 4 keys/lane, position i=lane*4+r ----
    uint64_t v0 = sel[w][lane * 4 + 0];
    uint64_t v1 = sel[w][lane * 4 + 1];
    uint64_t v2 = sel[w][lane * 4 + 2];
    uint64_t v3 = sel[w][lane * 4 + 3];

#pragma unroll
    for (int k = 2; k <= 256; k <<= 1) {
#pragma unroll
        for (int j = 128; j >= 4; j >>= 1) {
            if (j <= (k >> 1)) {
                int lx = j >> 2;
                step_xor(v0, 0, lane, lx, k);
                step_xor(v1, 1, lane, lx, k);
                step_xor(v2, 2, lane, lx, k);
                step_xor(v3, 3, lane, lx, k);
            }
        }
        if (k >= 4) {
            bool d02 = (((lane * 4 + 0) & k) == 0);
            bool d13 = (((lane * 4 + 1) & k) == 0);
            cmpex(v0, v2, d02);
            cmpex(v1, v3, d13);
        }
        bool d01 = (((lane * 4 + 0) & k) == 0);
        bool d23 = (((lane * 4 + 2) & k) == 0);
        cmpex(v0, v1, d01);
        cmpex(v2, v3, d23);
    }

    // ---- unpack & store (rank = lane*4 + r), coalesced float4 ----
    uint64_t kk[4] = {v0, v1, v2, v3};
    float ov[4], oi[4];
#pragma unroll
    for (int r = 0; r < 4; ++r) {
        uint32_t s = (uint32_t)(kk[r] >> 16);
        ov[r] = __uint_as_float((s & 0x80000000u) ? (s & 0x7FFFFFFFu) : ~s);
        oi[r] = (float)(0xFFFFu ^ (uint32_t)(kk[r] & 0xFFFFu));
    }
    float4* out_v = (float4*)(out + (size_t)row * TOPK);
    float4* out_i = (float4*)(out + (size_t)NTOK * TOPK + (size_t)row * TOPK);
    out_v[lane] = make_float4(ov[0], ov[1], ov[2], ov[3]);
    out_i[lane] = make_float4(oi[0], oi[1], oi[2], oi[3]);
}

extern "C" void kernel_launch(void* const* d_in, const int* in_sizes, int n_in,
                              void* d_out, int out_size, void* d_ws, size_t ws_size,
                              hipStream_t stream) {
    const int*   ids = (const int*)d_in[0];
    const float* W   = (const float*)d_in[1];
    // d_in[2] is k == 256 (fixed), hard-coded as TOPK
    float* out = (float*)d_out;

    topk_kernel<<<NTOK / WPB, 256, 0, stream>>>(ids, W, out);
}